// Round 1
// 532.918 us; speedup vs baseline: 1.3664x; 1.3664x over previous
//
#include <hip/hip_runtime.h>

// ---------------------------------------------------------------------------
// MultiHeadAttention (softmax over QUERY axis) — MI355X / gfx950, bf16 MFMA.
// B=4, S=2048, D=1024, H=16, Dk=64. Inputs/outputs fp32.
// attn[i,j] = exp(s_ij)/L_j, L_j = sum_i exp(s_ij)   (column softmax)
// ws (64 MiB): Qb@0 | Kb@16MiB | Vb@32MiB | Xb@48MiB  (bf16 [B,H,S,Dk] / [B,S,D])
// Rl (1/L, 512 KiB fp32) parked in d_out, consumed before final GEMM.
//
// ROUND-6: attn_pv rewritten. Old: 64i/block, 32j steps, 128 barriers, K read
// from global per-wave, 8-way-conflicted Pl/Vs LDS ops -> 9% MfmaUtil, 5.2e7
// conflict cycles. New: 512 thr / 8 waves, 256i/block, 64j steps, ONE barrier
// per step, K staged via global_load_lds (pre-swizzled source, dbuf), V
// transpose-staged with conflict-free swizzle (dbuf, loads issued early /
// written late), wave-private swizzled P tile (no barrier for P), exp2 direct.
// LDS 64KB -> exactly 2 blocks/CU.
// ---------------------------------------------------------------------------

#define B_   4
#define S_   2048
#define D_   1024
#define H_   16
#define DK_  64
#define BH_  64
#define SCALE_  0.125f
#define EC_     50.0f     // exp clamp (natural-log domain), kept for colsum
#define SC2_    0.18033688f   // 0.125 * log2(e)
#define ECL_    72.134f       // 50 * log2(e)  (same clamp in exp2 domain)

typedef __bf16 bf16x2 __attribute__((ext_vector_type(2)));
typedef __bf16 bf16x4 __attribute__((ext_vector_type(4)));
typedef __bf16 bf16x8 __attribute__((ext_vector_type(8)));
typedef float  f32x4  __attribute__((ext_vector_type(4)));
typedef unsigned int u32;

#define MFMA16(a,b,c) __builtin_amdgcn_mfma_f32_16x16x32_bf16((a),(b),(c),0,0,0)

__device__ __forceinline__ bf16x8 ld8(const __bf16* p){ return *(const bf16x8*)p; }

// async global->LDS, 16B per lane; LDS dest = wave-uniform base + lane*16
__device__ __forceinline__ void gll16(const __bf16* g, __bf16* l) {
    __builtin_amdgcn_global_load_lds(
        (const __attribute__((address_space(1))) u32*)g,
        (__attribute__((address_space(3))) u32*)l, 16, 0, 0);
}

// ---------------------------------------------------------------------------
// GEMM  C[m][n] = sum_k A[m][k]*W[k][n] + bias[n]
//   128x128 tile, BK=32, 4 waves (2x2, 64x64 each), 16 MFMA/iter.
//   ABF16=1: A bf16, staged via global_load_lds (512 chunks of 16B, 2 phases).
//   ABF16=0: A fp32, vector-load + cvt + b128 LDS write (512 items, 2 phases).
//   W fp32 [k][n] -> Bs[n][k] bf16, packed k-pair b32 writes, chunk-XOR swizzle.
//   MODE 0: C fp32 [8192][1024]; MODE 1: C bf16 scatter [B,H,S,Dk].
// ---------------------------------------------------------------------------
template<int ABF16, int MODE>
__global__ __launch_bounds__(256) void gemm128(
    const void* __restrict__ Ap, const float* __restrict__ W,
    const float* __restrict__ bias, void* __restrict__ C)
{
    __shared__ __align__(16) __bf16 As[128*32];   // row-major, row stride 32 elem
    __shared__ __align__(16) __bf16 Bs[128*32];   // [n][k], swizzled 16B chunks

    const int t = threadIdx.x, lane = t & 63, w = t >> 6;
    const int wm = w >> 1, wn = w & 1;
    const int fr = lane & 15, fq = lane >> 4;
    const int m0 = blockIdx.y * 128, n0 = blockIdx.x * 128;

    f32x4 acc[4][4];
#pragma unroll
    for (int i = 0; i < 4; ++i)
#pragma unroll
        for (int j = 0; j < 4; ++j) acc[i][j] = (f32x4){0.f,0.f,0.f,0.f};

    for (int kk = 0; kk < D_; kk += 32) {
        __syncthreads();   // previous iteration's LDS reads complete
        if (ABF16) {
            const __bf16* Ab = (const __bf16*)Ap;
#pragma unroll
            for (int p = 0; p < 2; ++p) {
                int c = p*256 + t;
                gll16(&Ab[(size_t)(m0 + (c>>2))*D_ + kk + (c&3)*8],
                      &As[(size_t)(p*256 + (t & ~63))*8]);
            }
        } else {
            const float* Af = (const float*)Ap;
#pragma unroll
            for (int p = 0; p < 2; ++p) {
                int c = p*256 + t;
                int row = c >> 2, kc = (c & 3) * 8;
                const float* ap = &Af[(size_t)(m0 + row)*D_ + kk + kc];
                f32x4 x0 = *(const f32x4*)ap;
                f32x4 x1 = *(const f32x4*)(ap + 4);
                bf16x8 v = { (__bf16)x0[0], (__bf16)x0[1], (__bf16)x0[2], (__bf16)x0[3],
                             (__bf16)x1[0], (__bf16)x1[1], (__bf16)x1[2], (__bf16)x1[3] };
                *(bf16x8*)&As[row*32 + kc] = v;
            }
        }
        // W tile: 32k x 128n fp32 -> Bs[n][k] bf16 (pack k-pairs into b32)
#pragma unroll
        for (int p = 0; p < 2; ++p) {
            int idx = p*256 + t;
            int nq = idx >> 4, kp = idx & 15;              // n-quad, k-pair
            const float* wp = &W[(size_t)(kk + 2*kp)*D_ + n0 + nq*4];
            f32x4 w0 = *(const f32x4*)wp;
            f32x4 w1 = *(const f32x4*)(wp + D_);
#pragma unroll
            for (int u = 0; u < 4; ++u) {
                int n = nq*4 + u;
                bf16x2 v = { (__bf16)w0[u], (__bf16)w1[u] };
                *(bf16x2*)&Bs[n*32 + 8*((kp>>2) ^ (n&3)) + 2*(kp&3)] = v;
            }
        }
        __syncthreads();

        bf16x8 af[4], bfr[4];
#pragma unroll
        for (int mt = 0; mt < 4; ++mt)
            af[mt] = ld8(&As[(wm*64 + mt*16 + fr)*32 + fq*8]);
#pragma unroll
        for (int nt = 0; nt < 4; ++nt) {
            int n = wn*64 + nt*16 + fr;
            bfr[nt] = ld8(&Bs[n*32 + 8*(fq ^ (n & 3))]);
        }
#pragma unroll
        for (int mt = 0; mt < 4; ++mt)
#pragma unroll
            for (int nt = 0; nt < 4; ++nt)
                acc[mt][nt] = MFMA16(af[mt], bfr[nt], acc[mt][nt]);
    }

#pragma unroll
    for (int mt = 0; mt < 4; ++mt)
#pragma unroll
        for (int nt = 0; nt < 4; ++nt) {
            int colg = n0 + wn*64 + nt*16 + fr;
            float bv = bias[colg];
#pragma unroll
            for (int r = 0; r < 4; ++r) {
                int rowg = m0 + wm*64 + mt*16 + fq*4 + r;
                float o = acc[mt][nt][r] + bv;
                if (MODE == 0) {
                    ((float*)C)[(size_t)rowg*D_ + colg] = o;
                } else {
                    int b = rowg >> 11, sp = rowg & (S_-1);
                    int h = colg >> 6, dk = colg & 63;
                    ((__bf16*)C)[(((size_t)(b*H_ + h))*S_ + sp)*DK_ + dk] = (__bf16)o;
                }
            }
        }
}

// ---------------------------------------------------------------------------
// Column-softmax reciprocals: Rl[bh][j] = 1/sum_i exp(clamp(scale*Q_i·K_j)).
//   Block = 256 j (4 waves x 64 j); K-frags loop-invariant in regs.
//   Q tile (32 i x 64 dk) staged per step via global_load_lds, i&7 XOR swizzle.
// ---------------------------------------------------------------------------
__global__ __launch_bounds__(256) void colsum_rcp(
    const __bf16* __restrict__ Q, const __bf16* __restrict__ K,
    float* __restrict__ Rl)
{
    __shared__ __align__(16) __bf16 Qs[32*64];
    const int t = threadIdx.x, lane = t & 63, w = t >> 6;
    const int fr = lane & 15, fq = lane >> 4;
    const int bh = blockIdx.y;
    const int jw = blockIdx.x*256 + w*64;
    const __bf16* Qb = Q + (size_t)bh*S_*DK_;
    const __bf16* Kb = K + (size_t)bh*S_*DK_;

    bf16x8 kh[4][2];
#pragma unroll
    for (int jt = 0; jt < 4; ++jt) {
        const __bf16* kr = &Kb[(size_t)(jw + jt*16 + fr)*DK_];
        kh[jt][0] = ld8(kr + fq*8);
        kh[jt][1] = ld8(kr + 32 + fq*8);
    }

    float accl[4][4] = {};
    for (int i0 = 0; i0 < S_; i0 += 32) {
        __syncthreads();
        {   // chunk t -> row i=t>>3, phys chunk t&7 holds logical kq=(t&7)^(i&7)
            int i = t >> 3, kq = (t & 7) ^ (i & 7);
            gll16(&Qb[(size_t)(i0 + i)*DK_ + kq*8], &Qs[(size_t)(t & ~63)*8]);
        }
        __syncthreads();
#pragma unroll
        for (int it = 0; it < 2; ++it) {
            int i = it*16 + fr;
            bf16x8 q0 = ld8(&Qs[i*64 + 8*(fq ^ (i & 7))]);
            bf16x8 q1 = ld8(&Qs[i*64 + 8*((4 + fq) ^ (i & 7))]);
#pragma unroll
            for (int jt = 0; jt < 4; ++jt) {
                f32x4 s = MFMA16(kh[jt][0], q0, ((f32x4){0.f,0.f,0.f,0.f}));
                s = MFMA16(kh[jt][1], q1, s);
#pragma unroll
                for (int r = 0; r < 4; ++r)
                    accl[jt][r] += __expf(fminf(s[r]*SCALE_, EC_));
            }
        }
    }
#pragma unroll
    for (int jt = 0; jt < 4; ++jt)
#pragma unroll
        for (int r = 0; r < 4; ++r) {
            accl[jt][r] += __shfl_xor(accl[jt][r], 1, 64);
            accl[jt][r] += __shfl_xor(accl[jt][r], 2, 64);
            accl[jt][r] += __shfl_xor(accl[jt][r], 4, 64);
            accl[jt][r] += __shfl_xor(accl[jt][r], 8, 64);
        }
    if (fr == 0) {
#pragma unroll
        for (int jt = 0; jt < 4; ++jt)
#pragma unroll
            for (int r = 0; r < 4; ++r)
                Rl[(size_t)bh*S_ + jw + jt*16 + fq*4 + r] = 1.0f / accl[jt][r];
    }
}

// ---------------------------------------------------------------------------
// Pass 2 (REWRITTEN): X[i,:] = sum_j (exp2(clamp(s_ij*SC2)) * Rl_j) * V[j,:]
//
// 512 thr / 8 waves, i-tile 256 (32 i/wave), j-step 64, 32 steps, ONE barrier
// per step.  Per step per wave: 16 score MFMA + 16 PV MFMA (16x16x32 bf16).
//
// LDS (64 KB -> 2 blocks/CU):
//   Ks[2][64j][64dk]  dbuf, staged via global_load_lds with PRE-SWIZZLED global
//                     source: phys 16B chunk p of row j holds logical chunk
//                     p^(j&7).  ds_read_b128 frags aggregate-conflict-free.
//   Vs[2][64d][64j]   dbuf, transposed staging.  chunk swizzle p = m^((d^(d>>2))&7)
//                     -> b32 transpose writes land 2 lanes/bank (free), b128
//                     reads aggregate-even.
//   Pl[8][32i][64j]   WAVE-PRIVATE P tile (no barrier needed).  b64 chunk
//                     swizzle c' = c ^ (2*(i&7)) -> 4-way-even writes,
//                     conflict-free b128 reads.
//
// Schedule per step: [A] issue V reg-loads + Rl + gll16(next K)  ->
// [B] scores from Ks[cur] -> Pl  ->  [D] write Vs[cur] (V arrived under [B])
// -> barrier -> [G] PV from Pl + Vs[cur].   (T14 split; K dbuf hides gll16.)
// ---------------------------------------------------------------------------
__global__ __launch_bounds__(512, 4) void attn_pv(
    const __bf16* __restrict__ Q, const __bf16* __restrict__ K,
    const __bf16* __restrict__ V, const float* __restrict__ Rl,
    __bf16* __restrict__ X)
{
    __shared__ __align__(16) __bf16 Ks[2][64*64];   // 16 KB
    __shared__ __align__(16) __bf16 Vs[2][64*64];   // 16 KB
    __shared__ __align__(16) __bf16 Pl[8][32*64];   // 32 KB

    const int t = threadIdx.x, lane = t & 63, w = t >> 6;
    const int fr = lane & 15, fq = lane >> 4;
    const int bh = blockIdx.y;
    const int iw = blockIdx.x*256 + w*32;           // wave's i base
    const __bf16* Qb = Q + (size_t)bh*S_*DK_;
    const __bf16* Kb = K + (size_t)bh*S_*DK_;
    const __bf16* Vb = V + (size_t)bh*S_*DK_;
    const float*  Rb = Rl + (size_t)bh*S_;

    // Q fragments (B-operand: lane holds Q[i = iw+it*16+fr][kf*32+fq*8 ..+8])
    bf16x8 qf[2][2];
#pragma unroll
    for (int it = 0; it < 2; ++it)
#pragma unroll
        for (int kf = 0; kf < 2; ++kf)
            qf[it][kf] = ld8(&Qb[(size_t)(iw + it*16 + fr)*DK_ + kf*32 + fq*8]);

    // Vs staging task: thread t owns d-quad dq, j-pair jp (16 x 32 = 512)
    const int dq = t & 15, jp = t >> 4;
    // Ks staging: slot t -> row t>>3, phys chunk t&7 holds logical (t&7)^(row&7)
    const int krow = t >> 3;
    const int kchk = (t & 7) ^ (krow & 7);

    f32x4 acc[2][4];
#pragma unroll
    for (int it = 0; it < 2; ++it)
#pragma unroll
        for (int dt = 0; dt < 4; ++dt) acc[it][dt] = (f32x4){0.f,0.f,0.f,0.f};

    // prologue: stage Ks[0] (j tile 0)
    gll16(&Kb[(size_t)krow*DK_ + kchk*8], &Ks[0][(t & ~63)*8]);
    __syncthreads();

    for (int jg = 0; jg < S_; jg += 64) {
        const int cur = (jg >> 6) & 1;

        // ---- [A] issue V reg-loads + Rl loads, then prefetch next K tile ----
        bf16x4 v0 = *(const bf16x4*)&Vb[(size_t)(jg + 2*jp    )*DK_ + dq*4];
        bf16x4 v1 = *(const bf16x4*)&Vb[(size_t)(jg + 2*jp + 1)*DK_ + dq*4];
        f32x4 rl[4];
#pragma unroll
        for (int jt = 0; jt < 4; ++jt)
            rl[jt] = *(const f32x4*)&Rb[jg + jt*16 + fq*4];
        if (jg + 64 < S_)
            gll16(&Kb[(size_t)(jg + 64 + krow)*DK_ + kchk*8],
                  &Ks[cur ^ 1][(t & ~63)*8]);

        // ---- [B] scores: D[j][i] = K·Q^T, P = exp2(min(s*SC2,ECL))*Rl[j] ----
#pragma unroll
        for (int jt = 0; jt < 4; ++jt) {
            const __bf16* kb = &Ks[cur][(jt*16 + fr)*64];
            bf16x8 af0 = ld8(kb + ((fq    ) ^ (fr & 7))*8);
            bf16x8 af1 = ld8(kb + ((fq + 4) ^ (fr & 7))*8);
#pragma unroll
            for (int it = 0; it < 2; ++it) {
                f32x4 s = MFMA16(af0, qf[it][0], ((f32x4){0.f,0.f,0.f,0.f}));
                s = MFMA16(af1, qf[it][1], s);
                bf16x4 pv;
#pragma unroll
                for (int r = 0; r < 4; ++r)
                    pv[r] = (__bf16)(__builtin_amdgcn_exp2f(
                                fminf(s[r]*SC2_, ECL_)) * rl[jt][r]);
                int il = it*16 + fr;   // i local 0..31 ; P[j=jt*16+fq*4+r][il]
                *(bf16x4*)&Pl[w][il*64 + (((jt*4 + fq) ^ (2*(fr & 7))))*4] = pv;
            }
        }

        // ---- [D] Vs[cur][d][j] = V[j][d], swizzled (2 lanes/bank) ----
#pragma unroll
        for (int u = 0; u < 4; ++u) {
            int d = dq*4 + u;
            int f = (d ^ dq) & 7;                  // (d ^ (d>>2)) & 7
            *(bf16x2*)&Vs[cur][d*64 + (((jp >> 2) ^ f))*8 + (jp & 3)*2] =
                (bf16x2){ v0[u], v1[u] };
        }
        __syncthreads();   // Vs[cur] visible; also fences Ks/Vs buffer reuse

        // ---- [G] PV: acc[it][dt] += P(16i x 32j) · Vs(32j x 16d) ----
#pragma unroll
        for (int kh = 0; kh < 2; ++kh) {
            bf16x8 pa0 = ld8(&Pl[w][(     fr)*64 + (((fq + 4*kh) ^ (fr & 7)))*8]);
            bf16x8 pa1 = ld8(&Pl[w][(16 + fr)*64 + (((fq + 4*kh) ^ (fr & 7)))*8]);
#pragma unroll
            for (int dt = 0; dt < 4; ++dt) {
                int d = dt*16 + fr;
                int f = (d ^ (d >> 2)) & 7;
                bf16x8 vb = ld8(&Vs[cur][d*64 + (((kh*4 + fq) ^ f))*8]);
                acc[0][dt] = MFMA16(pa0, vb, acc[0][dt]);
                acc[1][dt] = MFMA16(pa1, vb, acc[1][dt]);
            }
        }
    }

    const int b = bh >> 4, h = bh & 15;
#pragma unroll
    for (int it = 0; it < 2; ++it)
#pragma unroll
        for (int dt = 0; dt < 4; ++dt)
#pragma unroll
            for (int r = 0; r < 4; ++r) {
                int i = iw + it*16 + fq*4 + r;
                X[((size_t)b*S_ + i)*D_ + h*DK_ + dt*16 + fr] =
                    (__bf16)acc[it][dt][r];
            }
}

// ---------------------------------------------------------------------------
// Host launcher
// ---------------------------------------------------------------------------
extern "C" void kernel_launch(void* const* d_in, const int* in_sizes, int n_in,
                              void* d_out, int out_size, void* d_ws, size_t ws_size,
                              hipStream_t stream)
{
    const float* query = (const float*)d_in[0];
    const float* key   = (const float*)d_in[1];
    const float* value = (const float*)d_in[2];
    const float* Wq = (const float*)d_in[3];  const float* bq = (const float*)d_in[4];
    const float* Wk = (const float*)d_in[5];  const float* bk = (const float*)d_in[6];
    const float* Wv = (const float*)d_in[7];  const float* bv = (const float*)d_in[8];
    const float* Wo = (const float*)d_in[9];  const float* bo = (const float*)d_in[10];

    char* ws = (char*)d_ws;
    const size_t MiB = 1024 * 1024;
    __bf16* Qb = (__bf16*)(ws);              // [B,H,S,Dk] 16 MiB
    __bf16* Kb = (__bf16*)(ws + 16 * MiB);
    __bf16* Vb = (__bf16*)(ws + 32 * MiB);
    __bf16* Xb = (__bf16*)(ws + 48 * MiB);   // [B,S,D]
    float*  Rlb = (float*)d_out;             // 512 KiB, consumed before final GEMM

    dim3 gg(D_/128, (B_*S_)/128);            // (8, 64)
    gemm128<0,1><<<gg, 256, 0, stream>>>(query, Wq, bq, Qb);
    gemm128<0,1><<<gg, 256, 0, stream>>>(key,   Wk, bk, Kb);
    gemm128<0,1><<<gg, 256, 0, stream>>>(value, Wv, bv, Vb);

    colsum_rcp<<<dim3(S_/256, BH_), 256, 0, stream>>>(Qb, Kb, Rlb);

    attn_pv<<<dim3(S_/256, BH_), 512, 0, stream>>>(Qb, Kb, Vb, Rlb, Xb);

    gemm128<1,0><<<gg, 256, 0, stream>>>(Xb, Wo, bo, d_out);
}

// Round 2
// 460.635 us; speedup vs baseline: 1.5808x; 1.1569x over previous
//
#include <hip/hip_runtime.h>

// ---------------------------------------------------------------------------
// MultiHeadAttention (softmax over QUERY axis) — MI355X / gfx950, bf16 MFMA.
// B=4, S=2048, D=1024, H=16, Dk=64. Inputs/outputs fp32.
// attn[i,j] = exp(s_ij)/L_j, L_j = sum_i exp(s_ij)   (column softmax)
//
// ws (64 MiB): Qb@0 | Kb@16MiB | Vb@32MiB | Xb@48MiB  (bf16 [B,H,S,Dk]/[B,S,D])
// d_out used as scratch until final GEMM:
//   Rl (1/L, 512 KiB fp32) @ +0 ;  WtQ/WtK/WtV (bf16 W^T, 2 MiB each) @ +1MiB.
//   WtO transposed into ws@0 (Qb region, dead after attn_pv).
//
// ROUND-7: (a) weights pre-transposed+cvt to bf16 [n][k] once (wtrans3) ->
// GEMM B-staging becomes 2x global_load_lds with pre-swizzled source (was:
// 8KB-strided fp32 loads + cvt + scalar LDS writes = the GEMM bottleneck).
// (b) As reads swizzle-fixed (were 8-way conflicted; same fix Bs already had).
// (c) colsum_rcp rewritten on the round-6 schedule: i-step 64, dbuf Qs via
// gll16 prefetch, ONE barrier/step (32 vs 128), exp2-direct.
// attn_pv unchanged from round-6 (107 us, verified).
// ---------------------------------------------------------------------------

#define B_   4
#define S_   2048
#define D_   1024
#define H_   16
#define DK_  64
#define BH_  64
#define SCALE_  0.125f
#define SC2_    0.18033688f   // 0.125 * log2(e)
#define ECL_    72.134f       // 50 * log2(e)  (exp clamp, exp2 domain)

typedef __bf16 bf16x2 __attribute__((ext_vector_type(2)));
typedef __bf16 bf16x4 __attribute__((ext_vector_type(4)));
typedef __bf16 bf16x8 __attribute__((ext_vector_type(8)));
typedef float  f32x4  __attribute__((ext_vector_type(4)));
typedef unsigned int u32;

#define MFMA16(a,b,c) __builtin_amdgcn_mfma_f32_16x16x32_bf16((a),(b),(c),0,0,0)

__device__ __forceinline__ bf16x8 ld8(const __bf16* p){ return *(const bf16x8*)p; }

// async global->LDS, 16B per lane; LDS dest = wave-uniform base + lane*16
__device__ __forceinline__ void gll16(const __bf16* g, __bf16* l) {
    __builtin_amdgcn_global_load_lds(
        (const __attribute__((address_space(1))) u32*)g,
        (__attribute__((address_space(3))) u32*)l, 16, 0, 0);
}

// ---------------------------------------------------------------------------
// wtrans3: W [k][n] fp32 -> Wt [n][k] bf16, NM matrices (blockIdx.z selects).
// 64x64 tile via LDS [64][80] (stride 160B: 16B-aligned, 2-lanes/bank).
// ---------------------------------------------------------------------------
__global__ __launch_bounds__(256) void wtrans3(
    const float* __restrict__ W0, const float* __restrict__ W1,
    const float* __restrict__ W2, __bf16* __restrict__ Wt)
{
    __shared__ __align__(16) __bf16 Ls[64][80];
    const int t = threadIdx.x;
    const int k0 = blockIdx.x * 64, n0 = blockIdx.y * 64, z = blockIdx.z;
    const float* W = (z == 0) ? W0 : ((z == 1) ? W1 : W2);
    __bf16* out = Wt + (size_t)z * D_ * D_;

#pragma unroll
    for (int p = 0; p < 4; ++p) {               // 1024 tasks: 64 k x 16 n-quads
        int id = p*256 + t;
        int k = id >> 4, nq = id & 15;
        f32x4 v = *(const f32x4*)&W[(size_t)(k0 + k)*D_ + n0 + nq*4];
#pragma unroll
        for (int u = 0; u < 4; ++u) Ls[nq*4 + u][k] = (__bf16)v[u];
    }
    __syncthreads();
#pragma unroll
    for (int p = 0; p < 2; ++p) {               // 512 tasks: 64 n x 8 chunks
        int id = p*256 + t;
        int n = id >> 3, c = id & 7;
        *(bf16x8*)&out[(size_t)(n0 + n)*D_ + k0 + c*8] =
            *(const bf16x8*)&Ls[n][c*8];
    }
}

// ---------------------------------------------------------------------------
// GEMM  C[m][n] = sum_k A[m][k]*Wt[n][k] + bias[n]     (Wt = W^T, bf16)
//   128x128 tile, BK=32, 4 waves (2x2, 64x64 each), 16 MFMA/iter.
//   B-staging: 2x gll16, source pre-swizzled (phys chunk c holds logical
//   c^(n&3)); read ld8 at chunk fq^(n&3)  -> aggregate-even banks.
//   A-staging: ABF16=1 same gll16 scheme; ABF16=0 fp32 reg-load+cvt, b128
//   write at swizzled chunk. As reads now swizzled too (was 8-way conflict).
//   MODE 0: C fp32 [8192][1024]; MODE 1: C bf16 scatter [B,H,S,Dk].
// ---------------------------------------------------------------------------
template<int ABF16, int MODE>
__global__ __launch_bounds__(256) void gemm128(
    const void* __restrict__ Ap, const __bf16* __restrict__ Wt,
    const float* __restrict__ bias, void* __restrict__ C)
{
    __shared__ __align__(16) __bf16 As[128*32];
    __shared__ __align__(16) __bf16 Bs[128*32];

    const int t = threadIdx.x, lane = t & 63, w = t >> 6;
    const int wm = w >> 1, wn = w & 1;
    const int fr = lane & 15, fq = lane >> 4;
    const int m0 = blockIdx.y * 128, n0 = blockIdx.x * 128;

    f32x4 acc[4][4];
#pragma unroll
    for (int i = 0; i < 4; ++i)
#pragma unroll
        for (int j = 0; j < 4; ++j) acc[i][j] = (f32x4){0.f,0.f,0.f,0.f};

    for (int kk = 0; kk < D_; kk += 32) {
        __syncthreads();   // previous iteration's LDS reads complete
        if (ABF16) {
            const __bf16* Ab = (const __bf16*)Ap;
#pragma unroll
            for (int p = 0; p < 2; ++p) {
                int c = p*256 + t;
                int row = c >> 2, l = (c & 3) ^ (row & 3);
                gll16(&Ab[(size_t)(m0 + row)*D_ + kk + l*8],
                      &As[(size_t)(p*256 + (t & ~63))*8]);
            }
        } else {
            const float* Af = (const float*)Ap;
#pragma unroll
            for (int p = 0; p < 2; ++p) {
                int c = p*256 + t;
                int row = c >> 2, ch = c & 3;
                const float* ap = &Af[(size_t)(m0 + row)*D_ + kk + ch*8];
                f32x4 x0 = *(const f32x4*)ap;
                f32x4 x1 = *(const f32x4*)(ap + 4);
                bf16x8 v = { (__bf16)x0[0], (__bf16)x0[1], (__bf16)x0[2], (__bf16)x0[3],
                             (__bf16)x1[0], (__bf16)x1[1], (__bf16)x1[2], (__bf16)x1[3] };
                *(bf16x8*)&As[row*32 + 8*(ch ^ (row & 3))] = v;
            }
        }
        // B tile: Wt rows are contiguous bf16 -> direct gll16, pre-swizzled
#pragma unroll
        for (int p = 0; p < 2; ++p) {
            int c = p*256 + t;
            int n = c >> 2, l = (c & 3) ^ (n & 3);
            gll16(&Wt[(size_t)(n0 + n)*D_ + kk + l*8],
                  &Bs[(size_t)(p*256 + (t & ~63))*8]);
        }
        __syncthreads();

        bf16x8 af[4], bfr[4];
#pragma unroll
        for (int mt = 0; mt < 4; ++mt) {
            int row = wm*64 + mt*16 + fr;
            af[mt] = ld8(&As[row*32 + 8*(fq ^ (row & 3))]);
        }
#pragma unroll
        for (int nt = 0; nt < 4; ++nt) {
            int n = wn*64 + nt*16 + fr;
            bfr[nt] = ld8(&Bs[n*32 + 8*(fq ^ (n & 3))]);
        }
#pragma unroll
        for (int mt = 0; mt < 4; ++mt)
#pragma unroll
            for (int nt = 0; nt < 4; ++nt)
                acc[mt][nt] = MFMA16(af[mt], bfr[nt], acc[mt][nt]);
    }

#pragma unroll
    for (int mt = 0; mt < 4; ++mt)
#pragma unroll
        for (int nt = 0; nt < 4; ++nt) {
            int colg = n0 + wn*64 + nt*16 + fr;
            float bv = bias[colg];
#pragma unroll
            for (int r = 0; r < 4; ++r) {
                int rowg = m0 + wm*64 + mt*16 + fq*4 + r;
                float o = acc[mt][nt][r] + bv;
                if (MODE == 0) {
                    ((float*)C)[(size_t)rowg*D_ + colg] = o;
                } else {
                    int b = rowg >> 11, sp = rowg & (S_-1);
                    int h = colg >> 6, dk = colg & 63;
                    ((__bf16*)C)[(((size_t)(b*H_ + h))*S_ + sp)*DK_ + dk] = (__bf16)o;
                }
            }
        }
}

// ---------------------------------------------------------------------------
// Column-softmax reciprocals: Rl[bh][j] = 1/sum_i exp2(clamp(s_ij*SC2)).
//   256 thr / 4 waves, wave owns 64 j; K-frags loop-invariant in regs.
//   i-step 64, Qs double-buffered via gll16 prefetch (pre-swizzled source,
//   i&7 chunk XOR), ONE barrier per step (32 steps).
// ---------------------------------------------------------------------------
__global__ __launch_bounds__(256) void colsum_rcp(
    const __bf16* __restrict__ Q, const __bf16* __restrict__ K,
    float* __restrict__ Rl)
{
    __shared__ __align__(16) __bf16 Qs[2][64*64];   // 16 KB
    const int t = threadIdx.x, lane = t & 63, w = t >> 6;
    const int fr = lane & 15, fq = lane >> 4;
    const int bh = blockIdx.y;
    const int jw = blockIdx.x*256 + w*64;
    const __bf16* Qb = Q + (size_t)bh*S_*DK_;
    const __bf16* Kb = K + (size_t)bh*S_*DK_;

    bf16x8 kh[4][2];
#pragma unroll
    for (int jt = 0; jt < 4; ++jt) {
        const __bf16* kr = &Kb[(size_t)(jw + jt*16 + fr)*DK_];
        kh[jt][0] = ld8(kr + fq*8);
        kh[jt][1] = ld8(kr + 32 + fq*8);
    }

    float accl[4][4] = {};

    // prologue: stage Qs[0] (rows 0..63), pre-swizzled source
#pragma unroll
    for (int p = 0; p < 2; ++p) {
        int c = p*256 + t;
        int i = c >> 3, l = (c & 7) ^ (i & 7);
        gll16(&Qb[(size_t)i*DK_ + l*8], &Qs[0][(size_t)(p*256 + (t & ~63))*8]);
    }
    __syncthreads();

    for (int i0 = 0; i0 < S_; i0 += 64) {
        const int cur = (i0 >> 6) & 1;
        if (i0 + 64 < S_) {
#pragma unroll
            for (int p = 0; p < 2; ++p) {
                int c = p*256 + t;
                int i = c >> 3, l = (c & 7) ^ (i & 7);
                gll16(&Qb[(size_t)(i0 + 64 + i)*DK_ + l*8],
                      &Qs[cur ^ 1][(size_t)(p*256 + (t & ~63))*8]);
            }
        }
#pragma unroll
        for (int it = 0; it < 4; ++it) {
            int i = it*16 + fr;
            bf16x8 q0 = ld8(&Qs[cur][i*64 + 8*(fq ^ (i & 7))]);
            bf16x8 q1 = ld8(&Qs[cur][i*64 + 8*((4 + fq) ^ (i & 7))]);
#pragma unroll
            for (int jt = 0; jt < 4; ++jt) {
                f32x4 s = MFMA16(kh[jt][0], q0, ((f32x4){0.f,0.f,0.f,0.f}));
                s = MFMA16(kh[jt][1], q1, s);
#pragma unroll
                for (int r = 0; r < 4; ++r)
                    accl[jt][r] += __builtin_amdgcn_exp2f(
                                       fminf(s[r]*SC2_, ECL_));
            }
        }
        __syncthreads();
    }
#pragma unroll
    for (int jt = 0; jt < 4; ++jt)
#pragma unroll
        for (int r = 0; r < 4; ++r) {
            accl[jt][r] += __shfl_xor(accl[jt][r], 1, 64);
            accl[jt][r] += __shfl_xor(accl[jt][r], 2, 64);
            accl[jt][r] += __shfl_xor(accl[jt][r], 4, 64);
            accl[jt][r] += __shfl_xor(accl[jt][r], 8, 64);
        }
    if (fr == 0) {
#pragma unroll
        for (int jt = 0; jt < 4; ++jt)
#pragma unroll
            for (int r = 0; r < 4; ++r)
                Rl[(size_t)bh*S_ + jw + jt*16 + fq*4 + r] = 1.0f / accl[jt][r];
    }
}

// ---------------------------------------------------------------------------
// Pass 2: X[i,:] = sum_j (exp2(clamp(s_ij*SC2)) * Rl_j) * V[j,:]
// (unchanged from round-6: 512 thr / 8 waves, 256 i, j-step 64, 1 barrier/step,
//  K dbuf via gll16 pre-swizzled, V transpose-staged swizzled, wave-private P)
// ---------------------------------------------------------------------------
__global__ __launch_bounds__(512, 4) void attn_pv(
    const __bf16* __restrict__ Q, const __bf16* __restrict__ K,
    const __bf16* __restrict__ V, const float* __restrict__ Rl,
    __bf16* __restrict__ X)
{
    __shared__ __align__(16) __bf16 Ks[2][64*64];   // 16 KB
    __shared__ __align__(16) __bf16 Vs[2][64*64];   // 16 KB
    __shared__ __align__(16) __bf16 Pl[8][32*64];   // 32 KB

    const int t = threadIdx.x, lane = t & 63, w = t >> 6;
    const int fr = lane & 15, fq = lane >> 4;
    const int bh = blockIdx.y;
    const int iw = blockIdx.x*256 + w*32;           // wave's i base
    const __bf16* Qb = Q + (size_t)bh*S_*DK_;
    const __bf16* Kb = K + (size_t)bh*S_*DK_;
    const __bf16* Vb = V + (size_t)bh*S_*DK_;
    const float*  Rb = Rl + (size_t)bh*S_;

    bf16x8 qf[2][2];
#pragma unroll
    for (int it = 0; it < 2; ++it)
#pragma unroll
        for (int kf = 0; kf < 2; ++kf)
            qf[it][kf] = ld8(&Qb[(size_t)(iw + it*16 + fr)*DK_ + kf*32 + fq*8]);

    const int dq = t & 15, jp = t >> 4;
    const int krow = t >> 3;
    const int kchk = (t & 7) ^ (krow & 7);

    f32x4 acc[2][4];
#pragma unroll
    for (int it = 0; it < 2; ++it)
#pragma unroll
        for (int dt = 0; dt < 4; ++dt) acc[it][dt] = (f32x4){0.f,0.f,0.f,0.f};

    gll16(&Kb[(size_t)krow*DK_ + kchk*8], &Ks[0][(t & ~63)*8]);
    __syncthreads();

    for (int jg = 0; jg < S_; jg += 64) {
        const int cur = (jg >> 6) & 1;

        bf16x4 v0 = *(const bf16x4*)&Vb[(size_t)(jg + 2*jp    )*DK_ + dq*4];
        bf16x4 v1 = *(const bf16x4*)&Vb[(size_t)(jg + 2*jp + 1)*DK_ + dq*4];
        f32x4 rl[4];
#pragma unroll
        for (int jt = 0; jt < 4; ++jt)
            rl[jt] = *(const f32x4*)&Rb[jg + jt*16 + fq*4];
        if (jg + 64 < S_)
            gll16(&Kb[(size_t)(jg + 64 + krow)*DK_ + kchk*8],
                  &Ks[cur ^ 1][(t & ~63)*8]);

#pragma unroll
        for (int jt = 0; jt < 4; ++jt) {
            const __bf16* kb = &Ks[cur][(jt*16 + fr)*64];
            bf16x8 af0 = ld8(kb + ((fq    ) ^ (fr & 7))*8);
            bf16x8 af1 = ld8(kb + ((fq + 4) ^ (fr & 7))*8);
#pragma unroll
            for (int it = 0; it < 2; ++it) {
                f32x4 s = MFMA16(af0, qf[it][0], ((f32x4){0.f,0.f,0.f,0.f}));
                s = MFMA16(af1, qf[it][1], s);
                bf16x4 pv;
#pragma unroll
                for (int r = 0; r < 4; ++r)
                    pv[r] = (__bf16)(__builtin_amdgcn_exp2f(
                                fminf(s[r]*SC2_, ECL_)) * rl[jt][r]);
                int il = it*16 + fr;
                *(bf16x4*)&Pl[w][il*64 + (((jt*4 + fq) ^ (2*(fr & 7))))*4] = pv;
            }
        }

#pragma unroll
        for (int u = 0; u < 4; ++u) {
            int d = dq*4 + u;
            int f = (d ^ dq) & 7;
            *(bf16x2*)&Vs[cur][d*64 + (((jp >> 2) ^ f))*8 + (jp & 3)*2] =
                (bf16x2){ v0[u], v1[u] };
        }
        __syncthreads();

#pragma unroll
        for (int kh = 0; kh < 2; ++kh) {
            bf16x8 pa0 = ld8(&Pl[w][(     fr)*64 + (((fq + 4*kh) ^ (fr & 7)))*8]);
            bf16x8 pa1 = ld8(&Pl[w][(16 + fr)*64 + (((fq + 4*kh) ^ (fr & 7)))*8]);
#pragma unroll
            for (int dt = 0; dt < 4; ++dt) {
                int d = dt*16 + fr;
                int f = (d ^ (d >> 2)) & 7;
                bf16x8 vb = ld8(&Vs[cur][d*64 + (((kh*4 + fq) ^ f))*8]);
                acc[0][dt] = MFMA16(pa0, vb, acc[0][dt]);
                acc[1][dt] = MFMA16(pa1, vb, acc[1][dt]);
            }
        }
    }

    const int b = bh >> 4, h = bh & 15;
#pragma unroll
    for (int it = 0; it < 2; ++it)
#pragma unroll
        for (int dt = 0; dt < 4; ++dt)
#pragma unroll
            for (int r = 0; r < 4; ++r) {
                int i = iw + it*16 + fq*4 + r;
                X[((size_t)b*S_ + i)*D_ + h*DK_ + dt*16 + fr] =
                    (__bf16)acc[it][dt][r];
            }
}

// ---------------------------------------------------------------------------
// Host launcher
// ---------------------------------------------------------------------------
extern "C" void kernel_launch(void* const* d_in, const int* in_sizes, int n_in,
                              void* d_out, int out_size, void* d_ws, size_t ws_size,
                              hipStream_t stream)
{
    const float* query = (const float*)d_in[0];
    const float* key   = (const float*)d_in[1];
    const float* value = (const float*)d_in[2];
    const float* Wq = (const float*)d_in[3];  const float* bq = (const float*)d_in[4];
    const float* Wk = (const float*)d_in[5];  const float* bk = (const float*)d_in[6];
    const float* Wv = (const float*)d_in[7];  const float* bv = (const float*)d_in[8];
    const float* Wo = (const float*)d_in[9];  const float* bo = (const float*)d_in[10];

    char* ws = (char*)d_ws;
    char* dob = (char*)d_out;
    const size_t MiB = 1024 * 1024;
    __bf16* Qb = (__bf16*)(ws);              // [B,H,S,Dk] 16 MiB
    __bf16* Kb = (__bf16*)(ws + 16 * MiB);
    __bf16* Vb = (__bf16*)(ws + 32 * MiB);
    __bf16* Xb = (__bf16*)(ws + 48 * MiB);   // [B,S,D]
    float*  Rlb = (float*)d_out;             // 512 KiB @ d_out+0
    __bf16* Wt3 = (__bf16*)(dob + 1 * MiB);  // WtQ|WtK|WtV, 2 MiB each
    __bf16* WtO = (__bf16*)(ws);             // Qb region, reused after attn_pv

    // weights -> W^T bf16 (scratch in d_out; dead until final GEMM)
    wtrans3<<<dim3(16,16,3), 256, 0, stream>>>(Wq, Wk, Wv, Wt3);

    dim3 gg(D_/128, (B_*S_)/128);            // (8, 64)
    gemm128<0,1><<<gg, 256, 0, stream>>>(query, Wt3,              bq, Qb);
    gemm128<0,1><<<gg, 256, 0, stream>>>(key,   Wt3 + (size_t)D_*D_,   bk, Kb);
    gemm128<0,1><<<gg, 256, 0, stream>>>(value, Wt3 + (size_t)2*D_*D_, bv, Vb);

    colsum_rcp<<<dim3(S_/256, BH_), 256, 0, stream>>>(Qb, Kb, Rlb);

    attn_pv<<<dim3(S_/256, BH_), 512, 0, stream>>>(Qb, Kb, Vb, Rlb, Xb);

    // Wo^T into Qb region (dead now); then final GEMM reads it from ws
    wtrans3<<<dim3(16,16,1), 256, 0, stream>>>(Wo, Wo, Wo, WtO);

    gemm128<1,0><<<gg, 256, 0, stream>>>(Xb, WtO, bo, d_out);
}

// Round 3
// 425.392 us; speedup vs baseline: 1.7118x; 1.0828x over previous
//
#include <hip/hip_runtime.h>

// ---------------------------------------------------------------------------
// MultiHeadAttention (softmax over QUERY axis) — MI355X / gfx950, bf16 MFMA.
// B=4, S=2048, D=1024, H=16, Dk=64. Inputs/outputs fp32.
// attn[i,j] = exp(s_ij)/L_j, L_j = sum_i exp(s_ij)   (column softmax)
//
// ws (64 MiB): Qb@0 | Kb@16MiB | Vb@32MiB | Xb@48MiB  (bf16 [B,H,S,Dk]/[B,S,D])
// d_out scratch until final GEMM: Rl@+0 (512KiB) | WtQ/WtK/WtV bf16 @+1MiB.
// WtO transposed into ws@0 (Qb region, dead after attn_pv).
//
// ROUND-8: (a) SC2 (0.125*log2e) folded into Q-projection epilogue -> score s
// arrives pre-scaled; exp path is now exp2(s)*rl (was mul+clamp+exp2+mul):
// -2 VALU ops per P element in attn_pv, -2 in colsum (clamp was 40-sigma dead
// code: s ~ N(0,1.4)). (b) XCD-aware 1D grids: bh = gid&63 puts all i-tiles
// of a (b,h) on ONE XCD -> K/V (512KB/bh) L2-resident (FETCH was 141MB vs
// 48MB ideal). Same for colsum Q re-reads and gemm A-panels (m = gid&63).
// (c) colsum regrid: 32 j/wave, 1024 blocks -> 4 blocks/CU (was 2), 16
// waves/CU; halves per-wave latency exposure.
// ---------------------------------------------------------------------------

#define B_   4
#define S_   2048
#define D_   1024
#define H_   16
#define DK_  64
#define BH_  64
#define SC2_    0.18033688f   // 0.125 * log2(e), folded into Q projection

typedef __bf16 bf16x2 __attribute__((ext_vector_type(2)));
typedef __bf16 bf16x4 __attribute__((ext_vector_type(4)));
typedef __bf16 bf16x8 __attribute__((ext_vector_type(8)));
typedef float  f32x4  __attribute__((ext_vector_type(4)));
typedef unsigned int u32;

#define MFMA16(a,b,c) __builtin_amdgcn_mfma_f32_16x16x32_bf16((a),(b),(c),0,0,0)

__device__ __forceinline__ bf16x8 ld8(const __bf16* p){ return *(const bf16x8*)p; }

// async global->LDS, 16B per lane; LDS dest = wave-uniform base + lane*16
__device__ __forceinline__ void gll16(const __bf16* g, __bf16* l) {
    __builtin_amdgcn_global_load_lds(
        (const __attribute__((address_space(1))) u32*)g,
        (__attribute__((address_space(3))) u32*)l, 16, 0, 0);
}

// ---------------------------------------------------------------------------
// wtrans3: W [k][n] fp32 -> Wt [n][k] bf16, 3 matrices (blockIdx.z selects).
// 64x64 tile via LDS [64][80] (stride 160B: 16B-aligned, 2-lanes/bank).
// ---------------------------------------------------------------------------
__global__ __launch_bounds__(256) void wtrans3(
    const float* __restrict__ W0, const float* __restrict__ W1,
    const float* __restrict__ W2, __bf16* __restrict__ Wt)
{
    __shared__ __align__(16) __bf16 Ls[64][80];
    const int t = threadIdx.x;
    const int k0 = blockIdx.x * 64, n0 = blockIdx.y * 64, z = blockIdx.z;
    const float* W = (z == 0) ? W0 : ((z == 1) ? W1 : W2);
    __bf16* out = Wt + (size_t)z * D_ * D_;

#pragma unroll
    for (int p = 0; p < 4; ++p) {               // 1024 tasks: 64 k x 16 n-quads
        int id = p*256 + t;
        int k = id >> 4, nq = id & 15;
        f32x4 v = *(const f32x4*)&W[(size_t)(k0 + k)*D_ + n0 + nq*4];
#pragma unroll
        for (int u = 0; u < 4; ++u) Ls[nq*4 + u][k] = (__bf16)v[u];
    }
    __syncthreads();
#pragma unroll
    for (int p = 0; p < 2; ++p) {               // 512 tasks: 64 n x 8 chunks
        int id = p*256 + t;
        int n = id >> 3, c = id & 7;
        *(bf16x8*)&out[(size_t)(n0 + n)*D_ + k0 + c*8] =
            *(const bf16x8*)&Ls[n][c*8];
    }
}

// ---------------------------------------------------------------------------
// GEMM  C[m][n] = (sum_k A[m][k]*Wt[n][k] + bias[n]) * scale   (Wt = W^T bf16)
//   128x128 tile, BK=32, 4 waves (2x2, 64x64 each), 16 MFMA/iter.
//   1D grid 512: m-tile = gid&63 (same-m blocks share an XCD -> A-panel L2-
//   resident), n-tile = gid>>6.
//   Staging via gll16 with pre-swizzled source chunks; reads swizzle-matched.
//   MODE 0: C fp32 [8192][1024]; MODE 1: C bf16 scatter [B,H,S,Dk].
//   QS: multiply output by SC2_ (Q projection only).
// ---------------------------------------------------------------------------
template<int ABF16, int MODE, int QS>
__global__ __launch_bounds__(256) void gemm128(
    const void* __restrict__ Ap, const __bf16* __restrict__ Wt,
    const float* __restrict__ bias, void* __restrict__ C)
{
    __shared__ __align__(16) __bf16 As[128*32];
    __shared__ __align__(16) __bf16 Bs[128*32];

    const int t = threadIdx.x, lane = t & 63, w = t >> 6;
    const int wm = w >> 1, wn = w & 1;
    const int fr = lane & 15, fq = lane >> 4;
    const int gid = blockIdx.x;
    const int m0 = (gid & 63) * 128, n0 = (gid >> 6) * 128;

    f32x4 acc[4][4];
#pragma unroll
    for (int i = 0; i < 4; ++i)
#pragma unroll
        for (int j = 0; j < 4; ++j) acc[i][j] = (f32x4){0.f,0.f,0.f,0.f};

    for (int kk = 0; kk < D_; kk += 32) {
        __syncthreads();   // previous iteration's LDS reads complete
        if (ABF16) {
            const __bf16* Ab = (const __bf16*)Ap;
#pragma unroll
            for (int p = 0; p < 2; ++p) {
                int c = p*256 + t;
                int row = c >> 2, l = (c & 3) ^ (row & 3);
                gll16(&Ab[(size_t)(m0 + row)*D_ + kk + l*8],
                      &As[(size_t)(p*256 + (t & ~63))*8]);
            }
        } else {
            const float* Af = (const float*)Ap;
#pragma unroll
            for (int p = 0; p < 2; ++p) {
                int c = p*256 + t;
                int row = c >> 2, ch = c & 3;
                const float* ap = &Af[(size_t)(m0 + row)*D_ + kk + ch*8];
                f32x4 x0 = *(const f32x4*)ap;
                f32x4 x1 = *(const f32x4*)(ap + 4);
                bf16x8 v = { (__bf16)x0[0], (__bf16)x0[1], (__bf16)x0[2], (__bf16)x0[3],
                             (__bf16)x1[0], (__bf16)x1[1], (__bf16)x1[2], (__bf16)x1[3] };
                *(bf16x8*)&As[row*32 + 8*(ch ^ (row & 3))] = v;
            }
        }
        // B tile: Wt rows contiguous bf16 -> gll16, pre-swizzled source
#pragma unroll
        for (int p = 0; p < 2; ++p) {
            int c = p*256 + t;
            int n = c >> 2, l = (c & 3) ^ (n & 3);
            gll16(&Wt[(size_t)(n0 + n)*D_ + kk + l*8],
                  &Bs[(size_t)(p*256 + (t & ~63))*8]);
        }
        __syncthreads();

        bf16x8 af[4], bfr[4];
#pragma unroll
        for (int mt = 0; mt < 4; ++mt) {
            int row = wm*64 + mt*16 + fr;
            af[mt] = ld8(&As[row*32 + 8*(fq ^ (row & 3))]);
        }
#pragma unroll
        for (int nt = 0; nt < 4; ++nt) {
            int n = wn*64 + nt*16 + fr;
            bfr[nt] = ld8(&Bs[n*32 + 8*(fq ^ (n & 3))]);
        }
#pragma unroll
        for (int mt = 0; mt < 4; ++mt)
#pragma unroll
            for (int nt = 0; nt < 4; ++nt)
                acc[mt][nt] = MFMA16(af[mt], bfr[nt], acc[mt][nt]);
    }

#pragma unroll
    for (int mt = 0; mt < 4; ++mt)
#pragma unroll
        for (int nt = 0; nt < 4; ++nt) {
            int colg = n0 + wn*64 + nt*16 + fr;
            float bv = bias[colg];
#pragma unroll
            for (int r = 0; r < 4; ++r) {
                int rowg = m0 + wm*64 + mt*16 + fq*4 + r;
                float o = acc[mt][nt][r] + bv;
                if (QS) o *= SC2_;
                if (MODE == 0) {
                    ((float*)C)[(size_t)rowg*D_ + colg] = o;
                } else {
                    int b = rowg >> 11, sp = rowg & (S_-1);
                    int h = colg >> 6, dk = colg & 63;
                    ((__bf16*)C)[(((size_t)(b*H_ + h))*S_ + sp)*DK_ + dk] = (__bf16)o;
                }
            }
        }
}

// ---------------------------------------------------------------------------
// Column-softmax reciprocals: Rl[bh][j] = 1/sum_i exp2(s_ij)   (s pre-scaled).
//   1024 blocks (1D, bh = gid&63 -> XCD-local Q), 4 waves x 32 j each.
//   K-frags loop-invariant in regs; i-step 64, Qs dbuf via gll16 prefetch
//   (pre-swizzled source, i&7 chunk XOR), ONE barrier per step.
// ---------------------------------------------------------------------------
__global__ __launch_bounds__(256) void colsum_rcp(
    const __bf16* __restrict__ Q, const __bf16* __restrict__ K,
    float* __restrict__ Rl)
{
    __shared__ __align__(16) __bf16 Qs[2][64*64];   // 16 KB
    const int t = threadIdx.x, lane = t & 63, w = t >> 6;
    const int fr = lane & 15, fq = lane >> 4;
    const int gid = blockIdx.x;
    const int bh = gid & 63;
    const int jw = (gid >> 6)*128 + w*32;
    const __bf16* Qb = Q + (size_t)bh*S_*DK_;
    const __bf16* Kb = K + (size_t)bh*S_*DK_;

    bf16x8 kh[2][2];
#pragma unroll
    for (int jt = 0; jt < 2; ++jt) {
        const __bf16* kr = &Kb[(size_t)(jw + jt*16 + fr)*DK_];
        kh[jt][0] = ld8(kr + fq*8);
        kh[jt][1] = ld8(kr + 32 + fq*8);
    }

    float accl[2][4] = {};

    // prologue: stage Qs[0] (rows 0..63), pre-swizzled source
#pragma unroll
    for (int p = 0; p < 2; ++p) {
        int c = p*256 + t;
        int i = c >> 3, l = (c & 7) ^ (i & 7);
        gll16(&Qb[(size_t)i*DK_ + l*8], &Qs[0][(size_t)(p*256 + (t & ~63))*8]);
    }
    __syncthreads();

    for (int i0 = 0; i0 < S_; i0 += 64) {
        const int cur = (i0 >> 6) & 1;
        if (i0 + 64 < S_) {
#pragma unroll
            for (int p = 0; p < 2; ++p) {
                int c = p*256 + t;
                int i = c >> 3, l = (c & 7) ^ (i & 7);
                gll16(&Qb[(size_t)(i0 + 64 + i)*DK_ + l*8],
                      &Qs[cur ^ 1][(size_t)(p*256 + (t & ~63))*8]);
            }
        }
#pragma unroll
        for (int it = 0; it < 4; ++it) {
            int i = it*16 + fr;
            bf16x8 q0 = ld8(&Qs[cur][i*64 + 8*(fq ^ (i & 7))]);
            bf16x8 q1 = ld8(&Qs[cur][i*64 + 8*((4 + fq) ^ (i & 7))]);
#pragma unroll
            for (int jt = 0; jt < 2; ++jt) {
                f32x4 s = MFMA16(kh[jt][0], q0, ((f32x4){0.f,0.f,0.f,0.f}));
                s = MFMA16(kh[jt][1], q1, s);
#pragma unroll
                for (int r = 0; r < 4; ++r)
                    accl[jt][r] += __builtin_amdgcn_exp2f(s[r]);
            }
        }
        __syncthreads();
    }
#pragma unroll
    for (int jt = 0; jt < 2; ++jt)
#pragma unroll
        for (int r = 0; r < 4; ++r) {
            accl[jt][r] += __shfl_xor(accl[jt][r], 1, 64);
            accl[jt][r] += __shfl_xor(accl[jt][r], 2, 64);
            accl[jt][r] += __shfl_xor(accl[jt][r], 4, 64);
            accl[jt][r] += __shfl_xor(accl[jt][r], 8, 64);
        }
    if (fr == 0) {
#pragma unroll
        for (int jt = 0; jt < 2; ++jt)
#pragma unroll
            for (int r = 0; r < 4; ++r)
                Rl[(size_t)bh*S_ + jw + jt*16 + fq*4 + r] = 1.0f / accl[jt][r];
    }
}

// ---------------------------------------------------------------------------
// Pass 2: X[i,:] = sum_j (exp2(s_ij) * Rl_j) * V[j,:]   (s pre-scaled)
// 512 thr / 8 waves, 256 i, j-step 64, 1 barrier/step, K dbuf via gll16
// pre-swizzled, V transpose-staged swizzled, wave-private P.  1D grid 512,
// bh = gid&63 -> all i-tiles of a (b,h) on one XCD (K/V L2-resident).
// ---------------------------------------------------------------------------
__global__ __launch_bounds__(512, 4) void attn_pv(
    const __bf16* __restrict__ Q, const __bf16* __restrict__ K,
    const __bf16* __restrict__ V, const float* __restrict__ Rl,
    __bf16* __restrict__ X)
{
    __shared__ __align__(16) __bf16 Ks[2][64*64];   // 16 KB
    __shared__ __align__(16) __bf16 Vs[2][64*64];   // 16 KB
    __shared__ __align__(16) __bf16 Pl[8][32*64];   // 32 KB

    const int t = threadIdx.x, lane = t & 63, w = t >> 6;
    const int fr = lane & 15, fq = lane >> 4;
    const int gid = blockIdx.x;
    const int bh = gid & 63;
    const int iw = (gid >> 6)*256 + w*32;           // wave's i base
    const __bf16* Qb = Q + (size_t)bh*S_*DK_;
    const __bf16* Kb = K + (size_t)bh*S_*DK_;
    const __bf16* Vb = V + (size_t)bh*S_*DK_;
    const float*  Rb = Rl + (size_t)bh*S_;

    bf16x8 qf[2][2];
#pragma unroll
    for (int it = 0; it < 2; ++it)
#pragma unroll
        for (int kf = 0; kf < 2; ++kf)
            qf[it][kf] = ld8(&Qb[(size_t)(iw + it*16 + fr)*DK_ + kf*32 + fq*8]);

    const int dq = t & 15, jp = t >> 4;
    const int krow = t >> 3;
    const int kchk = (t & 7) ^ (krow & 7);

    f32x4 acc[2][4];
#pragma unroll
    for (int it = 0; it < 2; ++it)
#pragma unroll
        for (int dt = 0; dt < 4; ++dt) acc[it][dt] = (f32x4){0.f,0.f,0.f,0.f};

    gll16(&Kb[(size_t)krow*DK_ + kchk*8], &Ks[0][(t & ~63)*8]);
    __syncthreads();

    for (int jg = 0; jg < S_; jg += 64) {
        const int cur = (jg >> 6) & 1;

        bf16x4 v0 = *(const bf16x4*)&Vb[(size_t)(jg + 2*jp    )*DK_ + dq*4];
        bf16x4 v1 = *(const bf16x4*)&Vb[(size_t)(jg + 2*jp + 1)*DK_ + dq*4];
        f32x4 rl[4];
#pragma unroll
        for (int jt = 0; jt < 4; ++jt)
            rl[jt] = *(const f32x4*)&Rb[jg + jt*16 + fq*4];
        if (jg + 64 < S_)
            gll16(&Kb[(size_t)(jg + 64 + krow)*DK_ + kchk*8],
                  &Ks[cur ^ 1][(t & ~63)*8]);

#pragma unroll
        for (int jt = 0; jt < 4; ++jt) {
            const __bf16* kb = &Ks[cur][(jt*16 + fr)*64];
            bf16x8 af0 = ld8(kb + ((fq    ) ^ (fr & 7))*8);
            bf16x8 af1 = ld8(kb + ((fq + 4) ^ (fr & 7))*8);
#pragma unroll
            for (int it = 0; it < 2; ++it) {
                f32x4 s = MFMA16(af0, qf[it][0], ((f32x4){0.f,0.f,0.f,0.f}));
                s = MFMA16(af1, qf[it][1], s);
                bf16x4 pv;
#pragma unroll
                for (int r = 0; r < 4; ++r)
                    pv[r] = (__bf16)(__builtin_amdgcn_exp2f(s[r]) * rl[jt][r]);
                int il = it*16 + fr;
                *(bf16x4*)&Pl[w][il*64 + (((jt*4 + fq) ^ (2*(fr & 7))))*4] = pv;
            }
        }

#pragma unroll
        for (int u = 0; u < 4; ++u) {
            int d = dq*4 + u;
            int f = (d ^ dq) & 7;
            *(bf16x2*)&Vs[cur][d*64 + (((jp >> 2) ^ f))*8 + (jp & 3)*2] =
                (bf16x2){ v0[u], v1[u] };
        }
        __syncthreads();

#pragma unroll
        for (int kh = 0; kh < 2; ++kh) {
            bf16x8 pa0 = ld8(&Pl[w][(     fr)*64 + (((fq + 4*kh) ^ (fr & 7)))*8]);
            bf16x8 pa1 = ld8(&Pl[w][(16 + fr)*64 + (((fq + 4*kh) ^ (fr & 7)))*8]);
#pragma unroll
            for (int dt = 0; dt < 4; ++dt) {
                int d = dt*16 + fr;
                int f = (d ^ (d >> 2)) & 7;
                bf16x8 vb = ld8(&Vs[cur][d*64 + (((kh*4 + fq) ^ f))*8]);
                acc[0][dt] = MFMA16(pa0, vb, acc[0][dt]);
                acc[1][dt] = MFMA16(pa1, vb, acc[1][dt]);
            }
        }
    }

    const int b = bh >> 4, h = bh & 15;
#pragma unroll
    for (int it = 0; it < 2; ++it)
#pragma unroll
        for (int dt = 0; dt < 4; ++dt)
#pragma unroll
            for (int r = 0; r < 4; ++r) {
                int i = iw + it*16 + fq*4 + r;
                X[((size_t)b*S_ + i)*D_ + h*DK_ + dt*16 + fr] =
                    (__bf16)acc[it][dt][r];
            }
}

// ---------------------------------------------------------------------------
// Host launcher
// ---------------------------------------------------------------------------
extern "C" void kernel_launch(void* const* d_in, const int* in_sizes, int n_in,
                              void* d_out, int out_size, void* d_ws, size_t ws_size,
                              hipStream_t stream)
{
    const float* query = (const float*)d_in[0];
    const float* key   = (const float*)d_in[1];
    const float* value = (const float*)d_in[2];
    const float* Wq = (const float*)d_in[3];  const float* bq = (const float*)d_in[4];
    const float* Wk = (const float*)d_in[5];  const float* bk = (const float*)d_in[6];
    const float* Wv = (const float*)d_in[7];  const float* bv = (const float*)d_in[8];
    const float* Wo = (const float*)d_in[9];  const float* bo = (const float*)d_in[10];

    char* ws = (char*)d_ws;
    char* dob = (char*)d_out;
    const size_t MiB = 1024 * 1024;
    __bf16* Qb = (__bf16*)(ws);              // [B,H,S,Dk] 16 MiB
    __bf16* Kb = (__bf16*)(ws + 16 * MiB);
    __bf16* Vb = (__bf16*)(ws + 32 * MiB);
    __bf16* Xb = (__bf16*)(ws + 48 * MiB);   // [B,S,D]
    float*  Rlb = (float*)d_out;             // 512 KiB @ d_out+0
    __bf16* Wt3 = (__bf16*)(dob + 1 * MiB);  // WtQ|WtK|WtV, 2 MiB each
    __bf16* WtO = (__bf16*)(ws);             // Qb region, reused after attn_pv

    // weights -> W^T bf16 (scratch in d_out; dead until final GEMM)
    wtrans3<<<dim3(16,16,3), 256, 0, stream>>>(Wq, Wk, Wv, Wt3);

    // projections (Q scaled by SC2_ in epilogue); 1D XCD-aware grid
    gemm128<0,1,1><<<512, 256, 0, stream>>>(query, Wt3,                  bq, Qb);
    gemm128<0,1,0><<<512, 256, 0, stream>>>(key,   Wt3 + (size_t)D_*D_,  bk, Kb);
    gemm128<0,1,0><<<512, 256, 0, stream>>>(value, Wt3 + (size_t)2*D_*D_,bv, Vb);

    colsum_rcp<<<1024, 256, 0, stream>>>(Qb, Kb, Rlb);

    attn_pv<<<512, 512, 0, stream>>>(Qb, Kb, Vb, Rlb, Xb);

    // Wo^T into Qb region (dead now); then final GEMM reads it from ws
    wtrans3<<<dim3(16,16,1), 256, 0, stream>>>(Wo, Wo, Wo, WtO);

    gemm128<1,0,0><<<512, 256, 0, stream>>>(Xb, WtO, bo, d_out);
}

// Round 5
// 373.491 us; speedup vs baseline: 1.9497x; 1.1390x over previous
//
#include <hip/hip_runtime.h>

// ---------------------------------------------------------------------------
// MultiHeadAttention (softmax over QUERY axis) — MI355X / gfx950, bf16 MFMA.
// B=4, S=2048, D=1024, H=16, Dk=64. Inputs/outputs fp32.
// attn[i,j] = exp(s_ij)/L_j, L_j = sum_i exp(s_ij)   (column softmax)
//
// ws (64 MiB): Qb@0 | Kb@16MiB | Vb@32MiB | Xb@48MiB  (bf16 [B,H,S,Dk]/[B,S,D])
// d_out scratch until final GEMM: Lg@+0 (512KiB) | WtQ/WtK/WtV bf16 @+1MiB.
// WtO transposed into ws@0 (Qb region, dead after attn_pv).
//
// ROUND-10 = ROUND-9 resubmit (container failed twice; source audited for
// OOB/race/hang — none found; concluding infra flake).
// ROUND-9: (a) gemm128 rewritten: BK=64, double-buffered LDS (64KB), ONE
// barrier per K-iter (was 2, zero overlap -> the dominant GEMM stall);
// next-tile loads issued before compute, fp32-A cvt+write after MFMAs (T14).
// (b) colsum stores -log2(L); attn_pv folds it into the score-MFMA C operand
// (C rows = j = lg's index) -> P = exp2(s), removing 32 v_mul/lane/step.
// (c) s_setprio(1/0) around attn_pv's PV MFMA cluster (T5).
// ---------------------------------------------------------------------------

#define B_   4
#define S_   2048
#define D_   1024
#define H_   16
#define DK_  64
#define BH_  64
#define SC2_    0.18033688f   // 0.125 * log2(e), folded into Q projection

typedef __bf16 bf16x2 __attribute__((ext_vector_type(2)));
typedef __bf16 bf16x4 __attribute__((ext_vector_type(4)));
typedef __bf16 bf16x8 __attribute__((ext_vector_type(8)));
typedef float  f32x4  __attribute__((ext_vector_type(4)));
typedef unsigned int u32;

#define MFMA16(a,b,c) __builtin_amdgcn_mfma_f32_16x16x32_bf16((a),(b),(c),0,0,0)

__device__ __forceinline__ bf16x8 ld8(const __bf16* p){ return *(const bf16x8*)p; }

// async global->LDS, 16B per lane; LDS dest = wave-uniform base + lane*16
__device__ __forceinline__ void gll16(const __bf16* g, __bf16* l) {
    __builtin_amdgcn_global_load_lds(
        (const __attribute__((address_space(1))) u32*)g,
        (__attribute__((address_space(3))) u32*)l, 16, 0, 0);
}

// ---------------------------------------------------------------------------
// wtrans3: W [k][n] fp32 -> Wt [n][k] bf16, 3 matrices (blockIdx.z selects).
// 64x64 tile via LDS [64][80] (stride 160B: 16B-aligned, 2-lanes/bank).
// ---------------------------------------------------------------------------
__global__ __launch_bounds__(256) void wtrans3(
    const float* __restrict__ W0, const float* __restrict__ W1,
    const float* __restrict__ W2, __bf16* __restrict__ Wt)
{
    __shared__ __align__(16) __bf16 Ls[64][80];
    const int t = threadIdx.x;
    const int k0 = blockIdx.x * 64, n0 = blockIdx.y * 64, z = blockIdx.z;
    const float* W = (z == 0) ? W0 : ((z == 1) ? W1 : W2);
    __bf16* out = Wt + (size_t)z * D_ * D_;

#pragma unroll
    for (int p = 0; p < 4; ++p) {               // 1024 tasks: 64 k x 16 n-quads
        int id = p*256 + t;
        int k = id >> 4, nq = id & 15;
        f32x4 v = *(const f32x4*)&W[(size_t)(k0 + k)*D_ + n0 + nq*4];
#pragma unroll
        for (int u = 0; u < 4; ++u) Ls[nq*4 + u][k] = (__bf16)v[u];
    }
    __syncthreads();
#pragma unroll
    for (int p = 0; p < 2; ++p) {               // 512 tasks: 64 n x 8 chunks
        int id = p*256 + t;
        int n = id >> 3, c = id & 7;
        *(bf16x8*)&out[(size_t)(n0 + n)*D_ + k0 + c*8] =
            *(const bf16x8*)&Ls[n][c*8];
    }
}

// ---------------------------------------------------------------------------
// GEMM  C[m][n] = (sum_k A[m][k]*Wt[n][k] + bias[n]) * scale   (Wt = W^T bf16)
//   128x128 tile, BK=64, DOUBLE-BUFFERED LDS, one barrier per K-iter (16).
//   4 waves (2x2, 64x64 each), 32 MFMA/iter.  1D grid 512: m = gid&63.
//   Row stride 64 elem (128 B): chunk swizzle c^(row&7) (8 chunks, 2 rows/
//   chunk = free).  bf16 A and all B staged via gll16 (pre-swizzled source);
//   fp32 A: reg-load at iter top, cvt+b128 LDS write AFTER the MFMAs (T14).
//   MODE 0: C fp32 [8192][1024]; MODE 1: C bf16 scatter [B,H,S,Dk].
//   QS: multiply output by SC2_ (Q projection only).
// ---------------------------------------------------------------------------
template<int ABF16, int MODE, int QS>
__global__ __launch_bounds__(256) void gemm128(
    const void* __restrict__ Ap, const __bf16* __restrict__ Wt,
    const float* __restrict__ bias, void* __restrict__ C)
{
    __shared__ __align__(16) __bf16 As[2][128*64];   // 16 KB x2
    __shared__ __align__(16) __bf16 Bs[2][128*64];   // 16 KB x2

    const int t = threadIdx.x, lane = t & 63, w = t >> 6;
    const int wm = w >> 1, wn = w & 1;
    const int fr = lane & 15, fq = lane >> 4;
    const int gid = blockIdx.x;
    const int m0 = (gid & 63) * 128, n0 = (gid >> 6) * 128;

    const __bf16* Ab = (const __bf16*)Ap;
    const float*  Af = (const float*)Ap;

    f32x4 acc[4][4];
#pragma unroll
    for (int i = 0; i < 4; ++i)
#pragma unroll
        for (int j = 0; j < 4; ++j) acc[i][j] = (f32x4){0.f,0.f,0.f,0.f};

    // staging task: idx = p*256+t (0..1023), row = idx>>3, phys chunk = idx&7,
    // logical chunk l = (idx&7)^(row&7); LDS offset = idx*8 (linear).
#define STAGE_B(kk, bsel)                                                     \
    _Pragma("unroll")                                                         \
    for (int p = 0; p < 4; ++p) {                                             \
        int idx = p*256 + t;                                                  \
        int n = idx >> 3, l = (idx & 7) ^ (n & 7);                            \
        gll16(&Wt[(size_t)(n0 + n)*D_ + (kk) + l*8],                          \
              &Bs[bsel][(size_t)(p*256 + (t & ~63))*8]);                      \
    }

#define STAGE_A_BF(kk, bsel)                                                  \
    _Pragma("unroll")                                                         \
    for (int p = 0; p < 4; ++p) {                                             \
        int idx = p*256 + t;                                                  \
        int row = idx >> 3, l = (idx & 7) ^ (row & 7);                        \
        gll16(&Ab[(size_t)(m0 + row)*D_ + (kk) + l*8],                        \
              &As[bsel][(size_t)(p*256 + (t & ~63))*8]);                      \
    }

#define LOAD_A_F32(kk, xa)                                                    \
    _Pragma("unroll")                                                         \
    for (int p = 0; p < 4; ++p) {                                             \
        int idx = p*256 + t;                                                  \
        int row = idx >> 3, l = (idx & 7) ^ (row & 7);                        \
        const float* ap = &Af[(size_t)(m0 + row)*D_ + (kk) + l*8];            \
        xa[2*p]   = *(const f32x4*)ap;                                        \
        xa[2*p+1] = *(const f32x4*)(ap + 4);                                  \
    }

#define WRITE_A_F32(xa, bsel)                                                 \
    _Pragma("unroll")                                                         \
    for (int p = 0; p < 4; ++p) {                                             \
        f32x4 x0 = xa[2*p], x1 = xa[2*p+1];                                   \
        bf16x8 v = { (__bf16)x0[0], (__bf16)x0[1], (__bf16)x0[2],             \
                     (__bf16)x0[3], (__bf16)x1[0], (__bf16)x1[1],             \
                     (__bf16)x1[2], (__bf16)x1[3] };                          \
        *(bf16x8*)&As[bsel][(size_t)(p*256 + t)*8] = v;                       \
    }

    // prologue: stage k-tile 0 into buffer 0
    if (ABF16) {
        STAGE_A_BF(0, 0)
    } else {
        f32x4 xa[8];
        LOAD_A_F32(0, xa)
        WRITE_A_F32(xa, 0)
    }
    STAGE_B(0, 0)
    __syncthreads();

    for (int kk = 0; kk < D_; kk += 64) {
        const int cur = (kk >> 6) & 1;
        const bool more = (kk + 64) < D_;

        f32x4 xa[8];
        if (more) {
            if (ABF16) {
                STAGE_A_BF(kk + 64, cur ^ 1)
            } else {
                LOAD_A_F32(kk + 64, xa)
            }
            STAGE_B(kk + 64, cur ^ 1)
        }

        // compute 2 k-halves from buffer cur
#pragma unroll
        for (int kh = 0; kh < 2; ++kh) {
            bf16x8 af[4], bfr[4];
#pragma unroll
            for (int mt = 0; mt < 4; ++mt) {
                int row = wm*64 + mt*16 + fr;
                af[mt] = ld8(&As[cur][row*64 + 8*((kh*4 + fq) ^ (row & 7))]);
            }
#pragma unroll
            for (int nt = 0; nt < 4; ++nt) {
                int n = wn*64 + nt*16 + fr;
                bfr[nt] = ld8(&Bs[cur][n*64 + 8*((kh*4 + fq) ^ (n & 7))]);
            }
#pragma unroll
            for (int mt = 0; mt < 4; ++mt)
#pragma unroll
                for (int nt = 0; nt < 4; ++nt)
                    acc[mt][nt] = MFMA16(af[mt], bfr[nt], acc[mt][nt]);
        }

        if (more && !ABF16) {
            WRITE_A_F32(xa, cur ^ 1)
        }
        __syncthreads();
    }
#undef STAGE_B
#undef STAGE_A_BF
#undef LOAD_A_F32
#undef WRITE_A_F32

#pragma unroll
    for (int mt = 0; mt < 4; ++mt)
#pragma unroll
        for (int nt = 0; nt < 4; ++nt) {
            int colg = n0 + wn*64 + nt*16 + fr;
            float bv = bias[colg];
#pragma unroll
            for (int r = 0; r < 4; ++r) {
                int rowg = m0 + wm*64 + mt*16 + fq*4 + r;
                float o = acc[mt][nt][r] + bv;
                if (QS) o *= SC2_;
                if (MODE == 0) {
                    ((float*)C)[(size_t)rowg*D_ + colg] = o;
                } else {
                    int b = rowg >> 11, sp = rowg & (S_-1);
                    int h = colg >> 6, dk = colg & 63;
                    ((__bf16*)C)[(((size_t)(b*H_ + h))*S_ + sp)*DK_ + dk] = (__bf16)o;
                }
            }
        }
}

// ---------------------------------------------------------------------------
// Column-softmax log-sums: Lg[bh][j] = -log2( sum_i exp2(s_ij) ).
//   1024 blocks (1D, bh = gid&63 -> XCD-local Q), 4 waves x 32 j each.
//   K-frags loop-invariant in regs; i-step 64, Qs dbuf via gll16 prefetch
//   (pre-swizzled source, i&7 chunk XOR), ONE barrier per step.
// ---------------------------------------------------------------------------
__global__ __launch_bounds__(256) void colsum_rcp(
    const __bf16* __restrict__ Q, const __bf16* __restrict__ K,
    float* __restrict__ Lg)
{
    __shared__ __align__(16) __bf16 Qs[2][64*64];   // 16 KB
    const int t = threadIdx.x, lane = t & 63, w = t >> 6;
    const int fr = lane & 15, fq = lane >> 4;
    const int gid = blockIdx.x;
    const int bh = gid & 63;
    const int jw = (gid >> 6)*128 + w*32;
    const __bf16* Qb = Q + (size_t)bh*S_*DK_;
    const __bf16* Kb = K + (size_t)bh*S_*DK_;

    bf16x8 kh[2][2];
#pragma unroll
    for (int jt = 0; jt < 2; ++jt) {
        const __bf16* kr = &Kb[(size_t)(jw + jt*16 + fr)*DK_];
        kh[jt][0] = ld8(kr + fq*8);
        kh[jt][1] = ld8(kr + 32 + fq*8);
    }

    float accl[2][4] = {};

    // prologue: stage Qs[0] (rows 0..63), pre-swizzled source
#pragma unroll
    for (int p = 0; p < 2; ++p) {
        int c = p*256 + t;
        int i = c >> 3, l = (c & 7) ^ (i & 7);
        gll16(&Qb[(size_t)i*DK_ + l*8], &Qs[0][(size_t)(p*256 + (t & ~63))*8]);
    }
    __syncthreads();

    for (int i0 = 0; i0 < S_; i0 += 64) {
        const int cur = (i0 >> 6) & 1;
        if (i0 + 64 < S_) {
#pragma unroll
            for (int p = 0; p < 2; ++p) {
                int c = p*256 + t;
                int i = c >> 3, l = (c & 7) ^ (i & 7);
                gll16(&Qb[(size_t)(i0 + 64 + i)*DK_ + l*8],
                      &Qs[cur ^ 1][(size_t)(p*256 + (t & ~63))*8]);
            }
        }
#pragma unroll
        for (int it = 0; it < 4; ++it) {
            int i = it*16 + fr;
            bf16x8 q0 = ld8(&Qs[cur][i*64 + 8*(fq ^ (i & 7))]);
            bf16x8 q1 = ld8(&Qs[cur][i*64 + 8*((4 + fq) ^ (i & 7))]);
#pragma unroll
            for (int jt = 0; jt < 2; ++jt) {
                f32x4 s = MFMA16(kh[jt][0], q0, ((f32x4){0.f,0.f,0.f,0.f}));
                s = MFMA16(kh[jt][1], q1, s);
#pragma unroll
                for (int r = 0; r < 4; ++r)
                    accl[jt][r] += __builtin_amdgcn_exp2f(s[r]);
            }
        }
        __syncthreads();
    }
#pragma unroll
    for (int jt = 0; jt < 2; ++jt)
#pragma unroll
        for (int r = 0; r < 4; ++r) {
            accl[jt][r] += __shfl_xor(accl[jt][r], 1, 64);
            accl[jt][r] += __shfl_xor(accl[jt][r], 2, 64);
            accl[jt][r] += __shfl_xor(accl[jt][r], 4, 64);
            accl[jt][r] += __shfl_xor(accl[jt][r], 8, 64);
        }
    if (fr == 0) {
#pragma unroll
        for (int jt = 0; jt < 2; ++jt)
#pragma unroll
            for (int r = 0; r < 4; ++r)
                Lg[(size_t)bh*S_ + jw + jt*16 + fq*4 + r] =
                    -__log2f(accl[jt][r]);
    }
}

// ---------------------------------------------------------------------------
// Pass 2: X[i,:] = sum_j exp2(s_ij + Lg_j) * V[j,:]   (s pre-scaled by SC2)
// Lg folded into the score-MFMA C operand (C rows = j).  512 thr / 8 waves,
// 256 i, j-step 64, 1 barrier/step, K dbuf via gll16 pre-swizzled, V
// transpose-staged swizzled, wave-private P, setprio around PV MFMAs.
// 1D grid 512, bh = gid&63 -> all i-tiles of a (b,h) on one XCD.
// ---------------------------------------------------------------------------
__global__ __launch_bounds__(512, 4) void attn_pv(
    const __bf16* __restrict__ Q, const __bf16* __restrict__ K,
    const __bf16* __restrict__ V, const float* __restrict__ Lg,
    __bf16* __restrict__ X)
{
    __shared__ __align__(16) __bf16 Ks[2][64*64];   // 16 KB
    __shared__ __align__(16) __bf16 Vs[2][64*64];   // 16 KB
    __shared__ __align__(16) __bf16 Pl[8][32*64];   // 32 KB

    const int t = threadIdx.x, lane = t & 63, w = t >> 6;
    const int fr = lane & 15, fq = lane >> 4;
    const int gid = blockIdx.x;
    const int bh = gid & 63;
    const int iw = (gid >> 6)*256 + w*32;           // wave's i base
    const __bf16* Qb = Q + (size_t)bh*S_*DK_;
    const __bf16* Kb = K + (size_t)bh*S_*DK_;
    const __bf16* Vb = V + (size_t)bh*S_*DK_;
    const float*  Rb = Lg + (size_t)bh*S_;

    bf16x8 qf[2][2];
#pragma unroll
    for (int it = 0; it < 2; ++it)
#pragma unroll
        for (int kf = 0; kf < 2; ++kf)
            qf[it][kf] = ld8(&Qb[(size_t)(iw + it*16 + fr)*DK_ + kf*32 + fq*8]);

    const int dq = t & 15, jp = t >> 4;
    const int krow = t >> 3;
    const int kchk = (t & 7) ^ (krow & 7);

    f32x4 acc[2][4];
#pragma unroll
    for (int it = 0; it < 2; ++it)
#pragma unroll
        for (int dt = 0; dt < 4; ++dt) acc[it][dt] = (f32x4){0.f,0.f,0.f,0.f};

    gll16(&Kb[(size_t)krow*DK_ + kchk*8], &Ks[0][(t & ~63)*8]);
    __syncthreads();

    for (int jg = 0; jg < S_; jg += 64) {
        const int cur = (jg >> 6) & 1;

        bf16x4 v0 = *(const bf16x4*)&Vb[(size_t)(jg + 2*jp    )*DK_ + dq*4];
        bf16x4 v1 = *(const bf16x4*)&Vb[(size_t)(jg + 2*jp + 1)*DK_ + dq*4];
        f32x4 lg[4];
#pragma unroll
        for (int jt = 0; jt < 4; ++jt)
            lg[jt] = *(const f32x4*)&Rb[jg + jt*16 + fq*4];
        if (jg + 64 < S_)
            gll16(&Kb[(size_t)(jg + 64 + krow)*DK_ + kchk*8],
                  &Ks[cur ^ 1][(t & ~63)*8]);

#pragma unroll
        for (int jt = 0; jt < 4; ++jt) {
            const __bf16* kb = &Ks[cur][(jt*16 + fr)*64];
            bf16x8 af0 = ld8(kb + ((fq    ) ^ (fr & 7))*8);
            bf16x8 af1 = ld8(kb + ((fq + 4) ^ (fr & 7))*8);
#pragma unroll
            for (int it = 0; it < 2; ++it) {
                f32x4 s = MFMA16(af0, qf[it][0], lg[jt]);   // C-init = -log2 L
                s = MFMA16(af1, qf[it][1], s);
                bf16x4 pv;
#pragma unroll
                for (int r = 0; r < 4; ++r)
                    pv[r] = (__bf16)__builtin_amdgcn_exp2f(s[r]);
                int il = it*16 + fr;
                *(bf16x4*)&Pl[w][il*64 + (((jt*4 + fq) ^ (2*(fr & 7))))*4] = pv;
            }
        }

#pragma unroll
        for (int u = 0; u < 4; ++u) {
            int d = dq*4 + u;
            int f = (d ^ dq) & 7;
            *(bf16x2*)&Vs[cur][d*64 + (((jp >> 2) ^ f))*8 + (jp & 3)*2] =
                (bf16x2){ v0[u], v1[u] };
        }
        __syncthreads();

        __builtin_amdgcn_s_setprio(1);
#pragma unroll
        for (int kh = 0; kh < 2; ++kh) {
            bf16x8 pa0 = ld8(&Pl[w][(     fr)*64 + (((fq + 4*kh) ^ (fr & 7)))*8]);
            bf16x8 pa1 = ld8(&Pl[w][(16 + fr)*64 + (((fq + 4*kh) ^ (fr & 7)))*8]);
#pragma unroll
            for (int dt = 0; dt < 4; ++dt) {
                int d = dt*16 + fr;
                int f = (d ^ (d >> 2)) & 7;
                bf16x8 vb = ld8(&Vs[cur][d*64 + (((kh*4 + fq) ^ f))*8]);
                acc[0][dt] = MFMA16(pa0, vb, acc[0][dt]);
                acc[1][dt] = MFMA16(pa1, vb, acc[1][dt]);
            }
        }
        __builtin_amdgcn_s_setprio(0);
    }

    const int b = bh >> 4, h = bh & 15;
#pragma unroll
    for (int it = 0; it < 2; ++it)
#pragma unroll
        for (int dt = 0; dt < 4; ++dt)
#pragma unroll
            for (int r = 0; r < 4; ++r) {
                int i = iw + it*16 + fq*4 + r;
                X[((size_t)b*S_ + i)*D_ + h*DK_ + dt*16 + fr] =
                    (__bf16)acc[it][dt][r];
            }
}

// ---------------------------------------------------------------------------
// Host launcher
// ---------------------------------------------------------------------------
extern "C" void kernel_launch(void* const* d_in, const int* in_sizes, int n_in,
                              void* d_out, int out_size, void* d_ws, size_t ws_size,
                              hipStream_t stream)
{
    const float* query = (const float*)d_in[0];
    const float* key   = (const float*)d_in[1];
    const float* value = (const float*)d_in[2];
    const float* Wq = (const float*)d_in[3];  const float* bq = (const float*)d_in[4];
    const float* Wk = (const float*)d_in[5];  const float* bk = (const float*)d_in[6];
    const float* Wv = (const float*)d_in[7];  const float* bv = (const float*)d_in[8];
    const float* Wo = (const float*)d_in[9];  const float* bo = (const float*)d_in[10];

    char* ws = (char*)d_ws;
    char* dob = (char*)d_out;
    const size_t MiB = 1024 * 1024;
    __bf16* Qb = (__bf16*)(ws);              // [B,H,S,Dk] 16 MiB
    __bf16* Kb = (__bf16*)(ws + 16 * MiB);
    __bf16* Vb = (__bf16*)(ws + 32 * MiB);
    __bf16* Xb = (__bf16*)(ws + 48 * MiB);   // [B,S,D]
    float*  Lgb = (float*)d_out;             // 512 KiB @ d_out+0 (-log2 L)
    __bf16* Wt3 = (__bf16*)(dob + 1 * MiB);  // WtQ|WtK|WtV, 2 MiB each
    __bf16* WtO = (__bf16*)(ws);             // Qb region, reused after attn_pv

    // weights -> W^T bf16 (scratch in d_out; dead until final GEMM)
    wtrans3<<<dim3(16,16,3), 256, 0, stream>>>(Wq, Wk, Wv, Wt3);

    // projections (Q scaled by SC2_ in epilogue); 1D XCD-aware grid
    gemm128<0,1,1><<<512, 256, 0, stream>>>(query, Wt3,                  bq, Qb);
    gemm128<0,1,0><<<512, 256, 0, stream>>>(key,   Wt3 + (size_t)D_*D_,  bk, Kb);
    gemm128<0,1,0><<<512, 256, 0, stream>>>(value, Wt3 + (size_t)2*D_*D_,bv, Vb);

    colsum_rcp<<<1024, 256, 0, stream>>>(Qb, Kb, Lgb);

    attn_pv<<<512, 512, 0, stream>>>(Qb, Kb, Vb, Lgb, Xb);

    // Wo^T into Qb region (dead now); then final GEMM reads it from ws
    wtrans3<<<dim3(16,16,1), 256, 0, stream>>>(Wo, Wo, Wo, WtO);

    gemm128<1,0,0><<<512, 256, 0, stream>>>(Xb, WtO, bo, d_out);
}